// Round 6
// baseline (132.926 us; speedup 1.0000x reference)
//
#include <hip/hip_runtime.h>
#include <hip/hip_fp16.h>
#include <math.h>

// AFM forward, SPLIT-KERNEL v4b (fault-proofed resubmit of R5).
// R5 never ran ("container failed twice", no counters). Prime suspect: K1
// wrote 11.5MB to d_ws without checking ws_size -> potential OOB global
// writes -> GPU fault -> container death. This version guards: if ws_size
// is too small, kernel_launch falls back to the proven baseline kernel
// (host branch on a capture-time constant; launches only; graph-safe).
// The dur_us self-identifies the path: ~124-125us = fallback ran.
//
// Theory under test (from R4 counters: FETCH 28.9MB = compulsory, HBM 7.4%
// peak, MfmaUtil 4.4%, VALUBusy 20%, Occ 40% -> LATENCY-bound, all pipes
// idle): decouple the gather regime from the compute regime.
//   K1 gather_scale: tiny-VGPR, 32 waves/CU, thread per 16B emb chunk,
//      4-lane groups read one 64B row coalesced, scale by fval, cvt to fp16,
//      write rows + fow[ix]*v products to d_ws. Pure MLP machine.
//   K2 afm_compute: proven baseline body (256,5), staging is a COALESCED
//      stream from d_ws (mostly L2/L3-warm) -> staging stall ~gone.
//
// Session laws (prev r6/r13/r15 + this r1/r2/r4):
// (1) launch_bounds caps below ~100 VGPR de-pipeline the compute body
//     (R4: 40-VGPR serialized code, +58% time, no scratch traffic);
// (2) exactly ONE inlined tile-loop instance per compute kernel;
// (3) in-wave gather/compute DMA pipelining is NEGATIVE at any occupancy;
// (4) traffic is compulsory (~29MB); HBM/request rate is NOT the limiter;
// (5) never write d_ws without checking ws_size.

#define BB 8192
#define FF 39
#define PP 741
#define NT 24                 // 32-pair tiles per sample; tile 23 has 5 valid
#define RBYTES 48             // fp16 row stride in LDS: 32B data + 16B pad
#define SBYTES (FF * RBYTES)  // 1872 B per sample
#define SF     (BB * FF)      // 319488 (sample,field) tasks
#define HROWS_B 0                     // ws offset: scaled fp16 rows [SF][32B]
#define FOWV_B  ((size_t)SF * 32)     // ws offset: fow[ix]*v products [SF] f32
#define WS_NEEDED ((size_t)SF * 36)   // 11,501,568 B

typedef _Float16 f16x8 __attribute__((ext_vector_type(8)));
typedef _Float16 h2    __attribute__((ext_vector_type(2)));
typedef __fp16   hw2   __attribute__((ext_vector_type(2)));  // builtin ABI type
typedef float    f32x4  __attribute__((ext_vector_type(4)));
typedef float    f32x16 __attribute__((ext_vector_type(16)));

// static pair table, transposed: v[n][k] = byte offsets of pair p = k*32+n,
// packed (i*RBYTES)<<16 | (j*RBYTES). Dead slots (p>=741) stay 0 (masked).
struct alignas(16) PijT { unsigned v[32][NT]; };
static constexpr PijT make_pij() {
    PijT t{};
    int p = 0;
    for (int i = 0; i < FF; ++i)
        for (int j = i + 1; j < FF; ++j) {
            t.v[p & 31][p >> 5] =
                ((unsigned)(i * RBYTES) << 16) | (unsigned)(j * RBYTES);
            ++p;
        }
    return t;
}
__device__ constexpr PijT c_pij = make_pij();

static __device__ __forceinline__ h2 cvt2(float lo, float hi) {
    return __builtin_bit_cast(h2, __builtin_amdgcn_cvt_pkrtz(lo, hi));
}
static __device__ __forceinline__ h2 ash2(unsigned d) {
    return __builtin_bit_cast(h2, d);
}
static __device__ __forceinline__ float fdot2f(h2 a, h2 b, float c) {
    return __builtin_amdgcn_fdot2(__builtin_bit_cast(hw2, a),
                                  __builtin_bit_cast(hw2, b), c, false);
}
static __device__ __forceinline__ h2 relu2(h2 x) {
    const h2 zz = {(_Float16)0.f, (_Float16)0.f};
    return __builtin_elementwise_max(x, zz);   // v_pk_max_f16
}

// ======================= shared compute body (inlined once per kernel) =====
// Computes the per-sample result given staged LDS rows (my) + fo partial.
// Kept as a macro-like inline so BOTH kernels contain exactly one instance.
static __device__ __forceinline__ void afm_body(
    const unsigned char* my, int lane, int n, int h, float fo,
    const float* aw_, const float* ab_, const float* ph_, const float* pp_,
    const float* bias, float* out, int smp)
{
    const float LOG2E = 1.44269504088896f;
    h2 hp0, hp1, hp2, hp3;
    {
        const f32x4 lo = ((const f32x4*)ph_)[h];
        const f32x4 hi = ((const f32x4*)ph_)[h + 2];
        hp0 = cvt2(lo[0] * LOG2E, lo[1] * LOG2E);
        hp1 = cvt2(lo[2] * LOG2E, lo[3] * LOG2E);
        hp2 = cvt2(hi[0] * LOG2E, hi[1] * LOG2E);
        hp3 = cvt2(hi[2] * LOG2E, hi[3] * LOG2E);
    }

    f32x16 cinit;                   // bias in rows a<16; rows >=16 zero
    {                               // (row 16 = proj_p row must have C=0)
        const f32x4 ab_lo = ((const f32x4*)ab_)[h];
        const f32x4 ab_hi = ((const f32x4*)ab_)[h + 2];
        cinit[0] = ab_lo[0]; cinit[1] = ab_lo[1];
        cinit[2] = ab_lo[2]; cinit[3] = ab_lo[3];
        cinit[4] = ab_hi[0]; cinit[5] = ab_hi[1];
        cinit[6] = ab_hi[2]; cinit[7] = ab_hi[3];
        #pragma unroll
        for (int r = 8; r < 16; ++r) cinit[r] = 0.f;
    }

    f16x8 wfrag;        // A: rows 0..15 = W^T, row 16 = proj_p, 17..31 zero
    {
        float t0 = 0.f, t1 = 0.f, t2 = 0.f, t3 = 0.f,
              t4 = 0.f, t5 = 0.f, t6 = 0.f, t7 = 0.f;
        if (n < 16) {
            const float* base = aw_ + (8 * h) * 16 + n;  // W[k=8h+j][m=n]
            t0 = base[0];   t1 = base[16];  t2 = base[32];  t3 = base[48];
            t4 = base[64];  t5 = base[80];  t6 = base[96];  t7 = base[112];
        } else if (n == 16) {
            const float* base = pp_ + 8 * h;             // p[k=8h+j]
            t0 = base[0]; t1 = base[1]; t2 = base[2]; t3 = base[3];
            t4 = base[4]; t5 = base[5]; t6 = base[6]; t7 = base[7];
        }
        union { h2 hh[4]; f16x8 v; } u;
        u.hh[0] = cvt2(t0, t1); u.hh[1] = cvt2(t2, t3);
        u.hh[2] = cvt2(t4, t5); u.hh[3] = cvt2(t6, t7);
        wfrag = u.v;
    }

    unsigned po[NT];                // 24 pair offsets in registers (L1 reads)
    {
        const uint4* myp4 = (const uint4*)c_pij.v[n];
        #pragma unroll
        for (int g = 0; g < 6; ++g) {
            uint4 q = myp4[g];
            po[4 * g + 0] = q.x; po[4 * g + 1] = q.y;
            po[4 * g + 2] = q.z; po[4 * g + 3] = q.w;
        }
    }

    const unsigned char* bpre = my + h * 16;    // this lane's e-half
    float aw = 0.f;                             // sum_p w_p * (bi_p . p)
    float z  = 0.f;                             // sum_p w_p (x2 across halves)

    uint4 di = *(const uint4*)(bpre + (po[0] >> 16));
    uint4 dj = *(const uint4*)(bpre + (po[0] & 0xFFFFu));

    #pragma unroll
    for (int t = 0; t < NT; ++t) {
        uint4 diN = di, djN = dj;
        if (t + 1 < NT) {                        // compile-time under unroll
            diN = *(const uint4*)(bpre + (po[t + 1] >> 16));
            djN = *(const uint4*)(bpre + (po[t + 1] & 0xFFFFu));
        }
        h2 m0 = ash2(di.x) * ash2(dj.x);         // v_pk_mul_f16
        h2 m1 = ash2(di.y) * ash2(dj.y);
        h2 m2 = ash2(di.z) * ash2(dj.z);
        h2 m3 = ash2(di.w) * ash2(dj.w);
        union { h2 hh[4]; f16x8 v; } u;
        u.hh[0] = m0; u.hh[1] = m1; u.hh[2] = m2; u.hh[3] = m3;
        f32x16 d = __builtin_amdgcn_mfma_f32_32x32x16_f16(wfrag, u.v,
                                                          cinit, 0, 0, 0);
        h2 c0 = relu2(cvt2(d[0], d[1]));
        h2 c1 = relu2(cvt2(d[2], d[3]));
        h2 c2 = relu2(cvt2(d[4], d[5]));
        h2 c3 = relu2(cvt2(d[6], d[7]));
        float s = fdot2f(c0, hp0,
                  fdot2f(c1, hp1,
                  fdot2f(c2, hp2,
                  fdot2f(c3, hp3, 0.f))));       // v_dot2_f32_f16 x4
        s += __shfl_xor(s, 32);                  // sum the two a-halves
        float w = __builtin_amdgcn_exp2f(s);
        if (t == NT - 1) w = (n < PP - (NT - 1) * 32) ? w : 0.f;
        z  += w;
        aw  = fmaf(w, d[8], aw);   // d[8]: row16 (=bi.p) on h=0, zero on h=1
        di = diN; dj = djN;
    }

    #pragma unroll
    for (int m = 1; m < 64; m <<= 1) {
        aw += __shfl_xor(aw, m);
        z  += __shfl_xor(z, m);
        fo += __shfl_xor(fo, m);
    }
    if (lane == 0) {
        // lane-sum aw counts each pair once; lane-sum z = 2*Z.
        float y = bias[0] + fo + 2.f * aw / z;
        out[smp] = 1.f / (1.f + __expf(-y));
    }
}

// ============================== K1: gather_scale ===========================
// thread t -> task (sf = t>>2, q = t&3): 16B chunk q of emb row fidx[sf],
// scaled by fval[sf], cvt to fp16, written to ws rows. q==0 lane also writes
// fow[ix]*v. 4-lane groups hit one 64B emb line; grid*256 == SF*4 exactly.
__global__ __launch_bounds__(256, 8)
void gather_scale(const int*   __restrict__ fidx,
                  const float* __restrict__ fval,
                  const float* __restrict__ fow,
                  const float* __restrict__ emb,
                  unsigned char* __restrict__ ws)
{
    const int t  = blockIdx.x * 256 + threadIdx.x;
    const int q  = t & 3;
    const int sf = t >> 2;          // < SF by construction (grid exact)

    const int   ix = fidx[sf];
    const float v  = fval[sf];

    const float4 e = ((const float4*)emb)[(size_t)(unsigned)ix * 4 + q];
    h2 a0 = cvt2(e.x * v, e.y * v);
    h2 a1 = cvt2(e.z * v, e.w * v);
    uint2 d = make_uint2(__builtin_bit_cast(unsigned, a0),
                         __builtin_bit_cast(unsigned, a1));
    *(uint2*)(ws + HROWS_B + (size_t)sf * 32 + q * 8) = d;

    if (q == 0)
        ((float*)(ws + FOWV_B))[sf] = fow[ix] * v;
}

// ============================== K2: afm_compute ============================
__global__ __launch_bounds__(256, 5)
void afm_compute(const unsigned char* __restrict__ ws,
                 const float* __restrict__ bias,
                 const float* __restrict__ aw_,
                 const float* __restrict__ ab_,
                 const float* __restrict__ ph_,
                 const float* __restrict__ pp_,
                 float*       __restrict__ out)
{
    __shared__ __align__(16) unsigned char s_emb[4 * SBYTES];  // 7488 B

    const int tid  = threadIdx.x;
    const int wid  = tid >> 6;
    const int lane = tid & 63;
    const int n    = lane & 31;
    const int h    = lane >> 5;
    const int smp  = blockIdx.x * 4 + wid;

    // stage scaled fp16 rows: COALESCED stream from ws (16B/lane)
    unsigned char* my = s_emb + wid * SBYTES;
    const unsigned char* src = ws + HROWS_B + (size_t)smp * (FF * 32);
    {
        uint4 d0 = *(const uint4*)(src + lane * 16);             // u = lane
        int r0 = lane >> 1, h0 = lane & 1;
        *(uint4*)(my + r0 * RBYTES + h0 * 16) = d0;
        if (lane < FF * 2 - 64) {                                // u = 64+lane
            uint4 d1 = *(const uint4*)(src + (64 + lane) * 16);
            int u1 = 64 + lane, r1 = u1 >> 1, h1 = u1 & 1;
            *(uint4*)(my + r1 * RBYTES + h1 * 16) = d1;
        }
    }

    // first-order partial: pre-multiplied products, coalesced
    float fo = (lane < FF)
             ? ((const float*)(ws + FOWV_B))[smp * FF + lane] : 0.f;

    afm_body(my, lane, n, h, fo, aw_, ab_, ph_, pp_, bias, out, smp);
}

// ===================== fallback: proven baseline (124-125us) ===============
__global__ __launch_bounds__(256, 5)
void afm_kernel(const int*   __restrict__ fidx,
                const float* __restrict__ fval,
                const float* __restrict__ fow,
                const float* __restrict__ emb,
                const float* __restrict__ bias,
                const float* __restrict__ aw_,
                const float* __restrict__ ab_,
                const float* __restrict__ ph_,
                const float* __restrict__ pp_,
                float*       __restrict__ out)
{
    __shared__ __align__(16) unsigned char s_emb[4 * SBYTES];  // 7488 B

    const int tid  = threadIdx.x;
    const int wid  = tid >> 6;
    const int lane = tid & 63;
    const int n    = lane & 31;
    const int h    = lane >> 5;
    const int smp  = blockIdx.x * 4 + wid;

    int ixr = 0; float vr = 0.f;
    if (lane < FF) {
        ixr = fidx[smp * FF + lane];
        vr  = fval[smp * FF + lane];
    }

    unsigned char* my = s_emb + wid * SBYTES;
    for (int u = lane; u < FF * 2; u += 64) {
        int row = u >> 1, hh = u & 1;
        int   ix = __shfl(ixr, row);
        float v  = __shfl(vr,  row);
        const float4* src = (const float4*)emb + (size_t)ix * 4 + hh * 2;
        float4 e0 = src[0], e1 = src[1];
        h2 a0 = cvt2(e0.x * v, e0.y * v);
        h2 a1 = cvt2(e0.z * v, e0.w * v);
        h2 a2 = cvt2(e1.x * v, e1.y * v);
        h2 a3 = cvt2(e1.z * v, e1.w * v);
        uint4 d = make_uint4(__builtin_bit_cast(unsigned, a0),
                             __builtin_bit_cast(unsigned, a1),
                             __builtin_bit_cast(unsigned, a2),
                             __builtin_bit_cast(unsigned, a3));
        *(uint4*)(my + row * RBYTES + hh * 16) = d;
    }

    float fo = (lane < FF) ? fow[ixr] * vr : 0.f;

    afm_body(my, lane, n, h, fo, aw_, ab_, ph_, pp_, bias, out, smp);
}

extern "C" void kernel_launch(void* const* d_in, const int* in_sizes, int n_in,
                              void* d_out, int out_size, void* d_ws, size_t ws_size,
                              hipStream_t stream) {
    const int*   fidx      = (const int*)  d_in[0];
    const float* fval      = (const float*)d_in[1];
    const float* fow       = (const float*)d_in[2];
    const float* emb_table = (const float*)d_in[3];
    const float* bias      = (const float*)d_in[4];
    const float* attn_w    = (const float*)d_in[5];
    const float* attn_b    = (const float*)d_in[6];
    const float* proj_h    = (const float*)d_in[7];
    const float* proj_p    = (const float*)d_in[8];
    float* out = (float*)d_out;

    if (d_ws != nullptr && ws_size >= WS_NEEDED) {
        unsigned char* ws = (unsigned char*)d_ws;
        // K1: 4992 blocks x 256 = SF*4 threads exactly
        gather_scale<<<(SF * 4) / 256, 256, 0, stream>>>(fidx, fval, fow,
                                                         emb_table, ws);
        // K2: proven baseline structure, staging from ws
        afm_compute<<<BB / 4, 256, 0, stream>>>(ws, bias, attn_w, attn_b,
                                                proj_h, proj_p, out);
    } else {
        afm_kernel<<<BB / 4, 256, 0, stream>>>(fidx, fval, fow, emb_table,
                                               bias, attn_w, attn_b,
                                               proj_h, proj_p, out);
    }
}

// Round 7
// 124.624 us; speedup vs baseline: 1.0666x; 1.0666x over previous
//
#include <hip/hip_runtime.h>
#include <hip/hip_fp16.h>
#include <math.h>

// AFM forward, FINAL (proven best: JSON 124.2-125.4us, kernel ~31.7us).
// One wave = one sample. Pooling folded INTO the MFMA via A-row 16 = proj_p
// (D[16][n] = bi.p arrives in d[8] of h=0 lanes; h=1 lanes read zero-row 20).
// Zero barriers (same-wave LDS ordering); constexpr pair table preloaded to
// registers (6 dwordx4, L1); fp16 scaled rows in LDS (RBYTES=48 pad);
// 1-tile-ahead ds_read prefetch; mfma_f32_32x32x16_f16 (K=16 exact); packed
// relu (v_pk_max_f16) + v_dot2_f32_f16 score; exp2 with h pre-scaled by
// log2(e); single 64-lane shuffle reduce of (aw, z, fo).
//
// SESSION LAWS (prior session r6/r13/r15 + this session r1/r2/r4/r6):
// (1) launch_bounds caps below ~100 VGPR de-pipeline the compute body
//     (r4: (256,6) -> 40-VGPR serialized code, +8.1us, no scratch traffic
//     -- the compiler serializes before it spills);
// (2) exactly ONE inlined tile-loop instance per kernel;
// (3) in-wave gather/compute DMA pipelining (global_load_lds + cvt pass +
//     fences) is NEGATIVE at any occupancy (r1: +2.7us @16w/CU, r2: +6.8us
//     @iso-20w/CU) -- inter-wave TLP already hides per-wave gather latency;
// (4) split gather/compute kernels via d_ws are NEGATIVE (r6: +8.7us) --
//     the 2x11.5MB ws round-trip + serialized dispatches cost more than the
//     latency exposure they remove;
// (5) traffic is compulsory (r4: FETCH 28.9MB matches hand count; HBM 7.4%
//     of peak) -- the kernel is latency-bound at the VGPR-pinned 20 waves/CU,
//     and the poison fills (2x268MB per iter, ~84us of the JSON number)
//     flush L2/L3 so no caching of the 64MB emb table survives iterations.
// Floor: random-gather latency + fixed harness overhead. Four structural
// alternatives measured worse; this structure stands.

#define BB 8192
#define FF 39
#define PP 741
#define NT 24                 // 32-pair tiles per sample; tile 23 has 5 valid
#define RBYTES 48             // fp16 row stride: 32B data + 16B pad
#define SBYTES (FF * RBYTES)  // 1872 B per sample

typedef _Float16 f16x8 __attribute__((ext_vector_type(8)));
typedef _Float16 h2    __attribute__((ext_vector_type(2)));
typedef __fp16   hw2   __attribute__((ext_vector_type(2)));  // builtin ABI type
typedef float    f32x4  __attribute__((ext_vector_type(4)));
typedef float    f32x16 __attribute__((ext_vector_type(16)));

// static pair table, transposed: v[n][k] = byte offsets of pair p = k*32+n,
// packed (i*RBYTES)<<16 | (j*RBYTES). Dead slots (p>=741) stay 0 (masked).
struct alignas(16) PijT { unsigned v[32][NT]; };
static constexpr PijT make_pij() {
    PijT t{};
    int p = 0;
    for (int i = 0; i < FF; ++i)
        for (int j = i + 1; j < FF; ++j) {
            t.v[p & 31][p >> 5] =
                ((unsigned)(i * RBYTES) << 16) | (unsigned)(j * RBYTES);
            ++p;
        }
    return t;
}
__device__ constexpr PijT c_pij = make_pij();

static __device__ __forceinline__ h2 cvt2(float lo, float hi) {
    return __builtin_bit_cast(h2, __builtin_amdgcn_cvt_pkrtz(lo, hi));
}
static __device__ __forceinline__ h2 ash2(unsigned d) {
    return __builtin_bit_cast(h2, d);
}
static __device__ __forceinline__ float fdot2f(h2 a, h2 b, float c) {
    return __builtin_amdgcn_fdot2(__builtin_bit_cast(hw2, a),
                                  __builtin_bit_cast(hw2, b), c, false);
}
static __device__ __forceinline__ h2 relu2(h2 x) {
    const h2 zz = {(_Float16)0.f, (_Float16)0.f};
    return __builtin_elementwise_max(x, zz);   // v_pk_max_f16
}

__global__ __launch_bounds__(256, 5)
void afm_kernel(const int*   __restrict__ fidx,
                const float* __restrict__ fval,
                const float* __restrict__ fow,
                const float* __restrict__ emb,
                const float* __restrict__ bias,
                const float* __restrict__ aw_,   // [E=16][A=16] row-major
                const float* __restrict__ ab_,   // [16]
                const float* __restrict__ ph_,   // [16]
                const float* __restrict__ pp_,   // [16]
                float*       __restrict__ out)
{
    __shared__ __align__(16) unsigned char s_emb[4 * SBYTES];  // 7488 B

    const int tid  = threadIdx.x;
    const int wid  = tid >> 6;
    const int lane = tid & 63;
    const int n    = lane & 31;      // pair slot within tile
    const int h    = lane >> 5;      // e-half / k-half
    const int smp  = blockIdx.x * 4 + wid;

    // ---- per-wave: indices + values ----
    int ixr = 0; float vr = 0.f;
    if (lane < FF) {
        ixr = fidx[smp * FF + lane];
        vr  = fval[smp * FF + lane];
    }

    // ---- stage scaled rows as fp16 (78 half-row tasks, same wave) ----
    unsigned char* my = s_emb + wid * SBYTES;
    for (int u = lane; u < FF * 2; u += 64) {
        int row = u >> 1, hh = u & 1;
        int   ix = __shfl(ixr, row);
        float v  = __shfl(vr,  row);
        const float4* src = (const float4*)emb + (size_t)ix * 4 + hh * 2;
        float4 e0 = src[0], e1 = src[1];
        h2 a0 = cvt2(e0.x * v, e0.y * v);
        h2 a1 = cvt2(e0.z * v, e0.w * v);
        h2 a2 = cvt2(e1.x * v, e1.y * v);
        h2 a3 = cvt2(e1.z * v, e1.w * v);
        uint4 d = make_uint4(__builtin_bit_cast(unsigned, a0),
                             __builtin_bit_cast(unsigned, a1),
                             __builtin_bit_cast(unsigned, a2),
                             __builtin_bit_cast(unsigned, a3));
        *(uint4*)(my + row * RBYTES + hh * 16) = d;
    }

    // ---- first-order partial (reduced at the very end with aw,z) ----
    float fo = (lane < FF) ? fow[ixr] * vr : 0.f;

    // ---- constant fragments ----
    const float LOG2E = 1.44269504088896f;
    // packed h coefficients (pre-scaled by log2 e), matching D-reg pair order:
    // regs 0..3 -> a = 4h + r ; regs 4..7 -> a = 8 + 4h + r
    h2 hp0, hp1, hp2, hp3;
    {
        const f32x4 lo = ((const f32x4*)ph_)[h];
        const f32x4 hi = ((const f32x4*)ph_)[h + 2];
        hp0 = cvt2(lo[0] * LOG2E, lo[1] * LOG2E);
        hp1 = cvt2(lo[2] * LOG2E, lo[3] * LOG2E);
        hp2 = cvt2(hi[0] * LOG2E, hi[1] * LOG2E);
        hp3 = cvt2(hi[2] * LOG2E, hi[3] * LOG2E);
    }

    f32x16 cinit;                   // bias in rows a<16; rows >=16 zero
    {                               // (row 16 = proj_p row must have C=0)
        const f32x4 ab_lo = ((const f32x4*)ab_)[h];
        const f32x4 ab_hi = ((const f32x4*)ab_)[h + 2];
        cinit[0] = ab_lo[0]; cinit[1] = ab_lo[1];
        cinit[2] = ab_lo[2]; cinit[3] = ab_lo[3];
        cinit[4] = ab_hi[0]; cinit[5] = ab_hi[1];
        cinit[6] = ab_hi[2]; cinit[7] = ab_hi[3];
        #pragma unroll
        for (int r = 8; r < 16; ++r) cinit[r] = 0.f;
    }

    f16x8 wfrag;        // A: rows 0..15 = W^T, row 16 = proj_p, 17..31 zero
    {
        float t0 = 0.f, t1 = 0.f, t2 = 0.f, t3 = 0.f,
              t4 = 0.f, t5 = 0.f, t6 = 0.f, t7 = 0.f;
        if (n < 16) {
            const float* base = aw_ + (8 * h) * 16 + n;  // W[k=8h+j][m=n]
            t0 = base[0];   t1 = base[16];  t2 = base[32];  t3 = base[48];
            t4 = base[64];  t5 = base[80];  t6 = base[96];  t7 = base[112];
        } else if (n == 16) {
            const float* base = pp_ + 8 * h;             // p[k=8h+j]
            t0 = base[0]; t1 = base[1]; t2 = base[2]; t3 = base[3];
            t4 = base[4]; t5 = base[5]; t6 = base[6]; t7 = base[7];
        }
        union { h2 hh[4]; f16x8 v; } u;
        u.hh[0] = cvt2(t0, t1); u.hh[1] = cvt2(t2, t3);
        u.hh[2] = cvt2(t4, t5); u.hh[3] = cvt2(t6, t7);
        wfrag = u.v;
    }

    // ---- preload all 24 pair offsets into registers (L1, 6 dwordx4) ----
    unsigned po[NT];
    {
        const uint4* myp4 = (const uint4*)c_pij.v[n];
        #pragma unroll
        for (int g = 0; g < 6; ++g) {
            uint4 q = myp4[g];
            po[4 * g + 0] = q.x; po[4 * g + 1] = q.y;
            po[4 * g + 2] = q.z; po[4 * g + 3] = q.w;
        }
    }

    // ---- main loop: 24 tiles, software-pipelined LDS reads (1 tile ahead) --
    const unsigned char* bpre = my + h * 16;    // this lane's e-half
    float aw = 0.f;                             // sum_p w_p * (bi_p . p)
    float z  = 0.f;                             // sum_p w_p (x2 across halves)

    uint4 di = *(const uint4*)(bpre + (po[0] >> 16));
    uint4 dj = *(const uint4*)(bpre + (po[0] & 0xFFFFu));

    #pragma unroll
    for (int t = 0; t < NT; ++t) {
        uint4 diN = di, djN = dj;
        if (t + 1 < NT) {                        // compile-time under unroll
            diN = *(const uint4*)(bpre + (po[t + 1] >> 16));
            djN = *(const uint4*)(bpre + (po[t + 1] & 0xFFFFu));
        }
        h2 m0 = ash2(di.x) * ash2(dj.x);         // v_pk_mul_f16
        h2 m1 = ash2(di.y) * ash2(dj.y);
        h2 m2 = ash2(di.z) * ash2(dj.z);
        h2 m3 = ash2(di.w) * ash2(dj.w);
        union { h2 hh[4]; f16x8 v; } u;
        u.hh[0] = m0; u.hh[1] = m1; u.hh[2] = m2; u.hh[3] = m3;
        f32x16 d = __builtin_amdgcn_mfma_f32_32x32x16_f16(wfrag, u.v,
                                                          cinit, 0, 0, 0);
        h2 c0 = relu2(cvt2(d[0], d[1]));
        h2 c1 = relu2(cvt2(d[2], d[3]));
        h2 c2 = relu2(cvt2(d[4], d[5]));
        h2 c3 = relu2(cvt2(d[6], d[7]));
        float s = fdot2f(c0, hp0,
                  fdot2f(c1, hp1,
                  fdot2f(c2, hp2,
                  fdot2f(c3, hp3, 0.f))));       // v_dot2_f32_f16 x4
        s += __shfl_xor(s, 32);                  // sum the two a-halves
        float w = __builtin_amdgcn_exp2f(s);
        if (t == NT - 1) w = (n < PP - (NT - 1) * 32) ? w : 0.f;
        z  += w;
        aw  = fmaf(w, d[8], aw);   // d[8]: row16 (=bi.p) on h=0, zero on h=1
        di = diN; dj = djN;
    }

    // ---- final reduce: aw, z, fo in one shuffle block ----
    #pragma unroll
    for (int m = 1; m < 64; m <<= 1) {
        aw += __shfl_xor(aw, m);
        z  += __shfl_xor(z, m);
        fo += __shfl_xor(fo, m);
    }
    if (lane == 0) {
        // lane-sum aw counts each pair once; lane-sum z = 2*Z.
        float y = bias[0] + fo + 2.f * aw / z;
        out[smp] = 1.f / (1.f + __expf(-y));
    }
}

extern "C" void kernel_launch(void* const* d_in, const int* in_sizes, int n_in,
                              void* d_out, int out_size, void* d_ws, size_t ws_size,
                              hipStream_t stream) {
    const int*   fidx      = (const int*)  d_in[0];
    const float* fval      = (const float*)d_in[1];
    const float* fow       = (const float*)d_in[2];
    const float* emb_table = (const float*)d_in[3];
    const float* bias      = (const float*)d_in[4];
    const float* attn_w    = (const float*)d_in[5];
    const float* attn_b    = (const float*)d_in[6];
    const float* proj_h    = (const float*)d_in[7];
    const float* proj_p    = (const float*)d_in[8];
    float* out = (float*)d_out;

    afm_kernel<<<BB / 4, 256, 0, stream>>>(fidx, fval, fow, emb_table, bias,
                                           attn_w, attn_b, proj_h, proj_p, out);
}